// Round 1
// baseline (6135.822 us; speedup 1.0000x reference)
//
#include <hip/hip_runtime.h>
#include <hip/hip_cooperative_groups.h>

namespace cg = cooperative_groups;

typedef __attribute__((ext_vector_type(8))) short short8;
typedef __attribute__((ext_vector_type(4))) float f32x4;

constexpr int H    = 516;    // hidden
constexpr int GP   = 2080;   // padded gate cols (65*32), permuted chat = 4*u+g
constexpr int KH   = 544;    // padded hidden K (17*32)
constexpr int KE   = 256;    // embedding dim
constexpr int NB   = 65;     // recurrence blocks (8 units each -> 520 padded units)
constexpr int SB   = 32;     // batch
constexpr int SEQ  = 64;
constexpr int MROW = 2048;   // SEQ*SB
constexpr int V    = 32000;
constexpr int NBN  = 250;    // V/128

__device__ __forceinline__ float bf2f(short s) {
  unsigned u = ((unsigned)(unsigned short)s) << 16;
  float f; __builtin_memcpy(&f, &u, 4); return f;
}
__device__ __forceinline__ short f2bf(float f) {
  unsigned u; __builtin_memcpy(&u, &f, 4);
  u += 0x7fffu + ((u >> 16) & 1u);
  return (short)(u >> 16);
}
__device__ __forceinline__ float sigm(float x){ return 1.f/(1.f+__expf(-x)); }
__device__ __forceinline__ float tanh_(float x){ float e=__expf(-2.f*x); return (1.f-e)/(1.f+e); }

// ---------------- pack kernels ----------------
// Recurrent weights into per-block MFMA B-fragment order:
// dst[((bid*2+nt)*ksteps+ks)*64+lane][8], value = W[n(chat)][k], chat=bid*32+nt*16+(lane&15),
// k = ks*32+(lane>>4)*8+j.  ksteps=17: single matrix (Whh). ksteps=34: [Wih1 | Whh1] concat.
__global__ void k_pack_gates(const float* __restrict__ W1, const float* __restrict__ W2,
                             short* __restrict__ dst, int ksteps) {
  int gid = blockIdx.x * 256 + threadIdx.x;
  int total = NB * 2 * ksteps * 64;
  if (gid >= total) return;
  int lane = gid & 63;
  int rest = gid >> 6;
  int ks = rest % ksteps; rest /= ksteps;
  int nt = rest & 1; int bid = rest >> 1;
  int chat = bid * 32 + nt * 16 + (lane & 15);
  int u = chat >> 2, g = chat & 3;
  int kb = ks * 32 + (lane >> 4) * 8;
  short8 v;
#pragma unroll
  for (int j = 0; j < 8; ++j) {
    int k = kb + j;
    const float* src = W1; int kk = k;
    if (k >= KH) { src = W2; kk = k - KH; }
    float f = 0.f;
    if (u < H && kk < H) f = src[(size_t)(g * H + u) * H + kk];
    v[j] = f2bf(f);
  }
  *(short8*)(dst + (size_t)gid * 8) = v;
}

// Wout -> bf16 [V][KH], K-padded with zeros
__global__ void k_pack_wout(const float* __restrict__ Wout, short* __restrict__ dst) {
  int gid = blockIdx.x * 256 + threadIdx.x;          // group of 8
  if (gid >= V * (KH / 8)) return;
  int row = gid / (KH / 8);
  int kb = (gid % (KH / 8)) * 8;
  short8 v;
#pragma unroll
  for (int j = 0; j < 8; ++j) {
    int k = kb + j;
    v[j] = f2bf(k < H ? Wout[(size_t)row * H + k] : 0.f);
  }
  *(short8*)(dst + (size_t)gid * 8) = v;
}

// Wih0 -> permuted-row bf16 [GP][KE]
__global__ void k_pack_wih(const float* __restrict__ Wih0, short* __restrict__ dst) {
  int gid = blockIdx.x * 256 + threadIdx.x;          // group of 8
  if (gid >= GP * (KE / 8)) return;
  int chat = gid / (KE / 8);
  int kb = (gid % (KE / 8)) * 8;
  int u = chat >> 2, g = chat & 3;
  short8 v;
#pragma unroll
  for (int j = 0; j < 8; ++j)
    v[j] = f2bf(u < H ? Wih0[(size_t)(g * H + u) * KE + kb + j] : 0.f);
  *(short8*)(dst + (size_t)gid * 8) = v;
}

// permuted biases: b0P = bih0+bhh0 (folded into X0), b1P = bih1+bhh1
__global__ void k_pack_bias(const float* ebih0, const float* ebhh0, const float* ebih1, const float* ebhh1,
                            const float* dbih0, const float* dbhh0, const float* dbih1, const float* dbhh1,
                            float* b0e, float* b1e, float* b0d, float* b1d) {
  int chat = blockIdx.x * 256 + threadIdx.x;
  if (chat >= GP) return;
  int u = chat >> 2, g = chat & 3, n = g * H + u;
  bool ok = (u < H);
  b0e[chat] = ok ? ebih0[n] + ebhh0[n] : 0.f;
  b1e[chat] = ok ? ebih1[n] + ebhh1[n] : 0.f;
  b0d[chat] = ok ? dbih0[n] + dbhh0[n] : 0.f;
  b1d[chat] = ok ? dbih1[n] + dbhh1[n] : 0.f;
}

// ---------------- batched input projection ----------------
// X0P[t][chat][b] = emb[tok[t*32+b]] . Wih0[n(chat)] + b0P[chat]
// MFMA: A = WihP[chat][k] bf16, B = emb row (fp32 -> bf16 on the fly). grid (130, 32), 4 waves.
__global__ void __launch_bounds__(256) k_embproj(const short* __restrict__ WihP,
                                                 const float* __restrict__ emb,
                                                 const int* __restrict__ toks,
                                                 const float* __restrict__ b0P,
                                                 float* __restrict__ X0P) {
  int tid = threadIdx.x, w = tid >> 6, lane = tid & 63, q = lane >> 4, col = lane & 15;
  int mt = blockIdx.x;                 // 0..129
  int ntile = blockIdx.y * 4 + w;      // 0..127
  int tb = ntile * 16 + col;
  int tok = toks[tb];
  const short* Ap = WihP + (size_t)(mt * 16 + col) * KE + q * 8;
  const float* Bp = emb + (size_t)tok * KE + q * 8;
  f32x4 acc = {0.f, 0.f, 0.f, 0.f};
#pragma unroll
  for (int ks = 0; ks < 8; ++ks) {
    short8 a = *(const short8*)(Ap + ks * 32);
    const f32x4* b4 = (const f32x4*)(Bp + ks * 32);
    f32x4 b0v = b4[0], b1v = b4[1];
    short8 bb;
    bb[0]=f2bf(b0v[0]); bb[1]=f2bf(b0v[1]); bb[2]=f2bf(b0v[2]); bb[3]=f2bf(b0v[3]);
    bb[4]=f2bf(b1v[0]); bb[5]=f2bf(b1v[1]); bb[6]=f2bf(b1v[2]); bb[7]=f2bf(b1v[3]);
    acc = __builtin_amdgcn_mfma_f32_16x16x32_bf16(a, bb, acc, 0, 0, 0);
  }
  int chat0 = mt * 16 + q * 4;
  f32x4 bias = *(const f32x4*)(b0P + chat0);
  int t = tb >> 5, b = tb & 31;
  float* dst = X0P + ((size_t)t * GP) * 32 + b;
#pragma unroll
  for (int r = 0; r < 4; ++r)
    dst[(size_t)(chat0 + r) * 32] = acc[r] + bias[r];
}

// ---------------- cooperative recurrence ----------------
struct RecArgs {
  const short *WAe, *WBe, *WAd, *WBd;
  const float *X0e, *X0d, *b1e, *b1d;
  short *h0g, *h1g, *H1P;   // h0g/h1g: double-buffered [2][32][KH] bf16
};

__global__ void __launch_bounds__(256) k_recur(RecArgs A) {
  int tid = threadIdx.x, lane = tid & 63, w = tid >> 6;
  int q = lane >> 4, col = lane & 15;
  int mt = w >> 1, nt = w & 1;
  int bid = blockIdx.x;
  int chat_l = nt * 16 + col, chat = bid * 32 + chat_l;
  int am = mt * 16 + col;               // A-fragment row (batch index)
  __shared__ float c0[32][8], c1[32][8];
  __shared__ float gbuf[32][33];
  int cb = tid >> 3, cu = tid & 7;      // cell-update: batch, local unit
  int hu = bid * 8 + cu;                // global unit
  c0[cb][cu] = 0.f; c1[cb][cu] = 0.f;
  cg::grid_group grid = cg::this_grid();
  __syncthreads();

  for (int g = 0; g < 128; ++g) {
    int phase = g >> 6, t = g & 63;
    int rp = g & 1, wp = rp ^ 1;
    const short* WA = (phase ? A.WAd : A.WAe) + (size_t)bid * 17408 + (size_t)(nt * 17 * 64 + lane) * 8;
    const short* WB = (phase ? A.WBd : A.WBe) + (size_t)bid * 34816 + (size_t)(nt * 34 * 64 + lane) * 8;
    const float* X0 = phase ? A.X0d : A.X0e;
    const float* b1 = phase ? A.b1d : A.b1e;

    // ---- layer 0: gates = X0[t] + h0 @ Whh0^T ----
    f32x4 acc = {0.f, 0.f, 0.f, 0.f};
    const short* Ar = A.h0g + rp * 17408 + am * KH + q * 8;
#pragma unroll
    for (int ks = 0; ks < 17; ++ks) {
      short8 af = *(const short8*)(Ar + ks * 32);
      short8 bf = *(const short8*)(WA + ks * 512);
      acc = __builtin_amdgcn_mfma_f32_16x16x32_bf16(af, bf, acc, 0, 0, 0);
    }
    f32x4 xv = *(const f32x4*)(X0 + ((size_t)t * GP + chat) * 32 + mt * 16 + q * 4);
#pragma unroll
    for (int r = 0; r < 4; ++r) gbuf[mt * 16 + q * 4 + r][chat_l] = acc[r] + xv[r];
    __syncthreads();
    {
      float gi = gbuf[cb][cu * 4 + 0], gf = gbuf[cb][cu * 4 + 1];
      float gg = gbuf[cb][cu * 4 + 2], go = gbuf[cb][cu * 4 + 3];
      float c = c0[cb][cu];
      float cn = sigm(gf) * c + sigm(gi) * tanh_(gg);
      float hn = sigm(go) * tanh_(cn);
      c0[cb][cu] = cn;
      A.h0g[wp * 17408 + cb * KH + hu] = f2bf(hn);
    }
    __threadfence();
    grid.sync();
    __threadfence();

    // ---- layer 1: gates = h0_t @ Wih1^T + h1 @ Whh1^T + b1 ----
    f32x4 acc2 = {0.f, 0.f, 0.f, 0.f};
    const short* Ar0 = A.h0g + wp * 17408 + am * KH + q * 8;
#pragma unroll
    for (int ks = 0; ks < 17; ++ks) {
      short8 af = *(const short8*)(Ar0 + ks * 32);
      short8 bf = *(const short8*)(WB + ks * 512);
      acc2 = __builtin_amdgcn_mfma_f32_16x16x32_bf16(af, bf, acc2, 0, 0, 0);
    }
    const short* Ar1 = A.h1g + rp * 17408 + am * KH + q * 8;
#pragma unroll
    for (int ks = 0; ks < 17; ++ks) {
      short8 af = *(const short8*)(Ar1 + ks * 32);
      short8 bf = *(const short8*)(WB + (size_t)(17 + ks) * 512);
      acc2 = __builtin_amdgcn_mfma_f32_16x16x32_bf16(af, bf, acc2, 0, 0, 0);
    }
    float bias1 = b1[chat];
#pragma unroll
    for (int r = 0; r < 4; ++r) gbuf[mt * 16 + q * 4 + r][chat_l] = acc2[r] + bias1;
    __syncthreads();
    {
      float gi = gbuf[cb][cu * 4 + 0], gf = gbuf[cb][cu * 4 + 1];
      float gg = gbuf[cb][cu * 4 + 2], go = gbuf[cb][cu * 4 + 3];
      float c = c1[cb][cu];
      float cn = sigm(gf) * c + sigm(gi) * tanh_(gg);
      float hn = sigm(go) * tanh_(cn);
      c1[cb][cu] = cn;
      short hb = f2bf(hn);
      A.h1g[wp * 17408 + cb * KH + hu] = hb;
      if (phase) A.H1P[((size_t)t * SB + cb) * KH + hu] = hb;
    }
    __threadfence();
    grid.sync();
    __threadfence();
  }
}

// ---------------- projection GEMM + streamed sum-exp ----------------
// 128x128 tile, 4 waves of 64x64, K=17 steps of 32. partials[row][bN] = sum_j exp(logit+bias)
__global__ void __launch_bounds__(256) k_project(const short* __restrict__ H1P,
                                                 const short* __restrict__ WoutP,
                                                 const float* __restrict__ bout,
                                                 float* __restrict__ partials) {
  int bM = blockIdx.x, bN = blockIdx.y;
  int tid = threadIdx.x, w = tid >> 6, lane = tid & 63, q = lane >> 4, col = lane & 15;
  int wm = w >> 1, wn = w & 1;
  __shared__ __align__(16) short As[128 * 32];
  __shared__ __align__(16) short Bs[128 * 32];
  __shared__ float sred[128][2];
  f32x4 acc[4][4];
#pragma unroll
  for (int mi = 0; mi < 4; ++mi)
#pragma unroll
    for (int ni = 0; ni < 4; ++ni) acc[mi][ni] = (f32x4){0.f, 0.f, 0.f, 0.f};

  for (int ks = 0; ks < 17; ++ks) {
#pragma unroll
    for (int i = 0; i < 2; ++i) {
      int chunk = tid * 2 + i;               // 0..511
      int row = chunk >> 2, ch = chunk & 3;
      ((short8*)As)[chunk] = *(const short8*)(H1P  + (size_t)(bM * 128 + row) * KH + ks * 32 + ch * 8);
      ((short8*)Bs)[chunk] = *(const short8*)(WoutP + (size_t)(bN * 128 + row) * KH + ks * 32 + ch * 8);
    }
    __syncthreads();
    short8 af[4], bf[4];
#pragma unroll
    for (int mi = 0; mi < 4; ++mi) af[mi] = *(const short8*)(As + (wm * 64 + mi * 16 + col) * 32 + q * 8);
#pragma unroll
    for (int ni = 0; ni < 4; ++ni) bf[ni] = *(const short8*)(Bs + (wn * 64 + ni * 16 + col) * 32 + q * 8);
#pragma unroll
    for (int mi = 0; mi < 4; ++mi)
#pragma unroll
      for (int ni = 0; ni < 4; ++ni)
        acc[mi][ni] = __builtin_amdgcn_mfma_f32_16x16x32_bf16(af[mi], bf[ni], acc[mi][ni], 0, 0, 0);
    __syncthreads();
  }
  float bias[4];
#pragma unroll
  for (int ni = 0; ni < 4; ++ni) bias[ni] = bout[bN * 128 + wn * 64 + ni * 16 + col];
#pragma unroll
  for (int mi = 0; mi < 4; ++mi) {
#pragma unroll
    for (int r = 0; r < 4; ++r) {
      float s = 0.f;
#pragma unroll
      for (int ni = 0; ni < 4; ++ni) s += __expf(acc[mi][ni][r] + bias[ni]);
      s += __shfl_xor(s, 1, 64); s += __shfl_xor(s, 2, 64);
      s += __shfl_xor(s, 4, 64); s += __shfl_xor(s, 8, 64);
      if (col == 0) sred[wm * 64 + mi * 16 + q * 4 + r][wn] = s;
    }
  }
  __syncthreads();
  if (tid < 128)
    partials[(size_t)(bM * 128 + tid) * NBN + bN] = sred[tid][0] + sred[tid][1];
}

// ---------------- finish: lse + target logit + loss ----------------
__global__ void __launch_bounds__(256) k_finish(const float* __restrict__ partials,
                                                const short* __restrict__ H1P,
                                                const float* __restrict__ Wout,
                                                const float* __restrict__ bout,
                                                const int* __restrict__ y,
                                                float* __restrict__ out) {
  int tid = threadIdx.x, w = tid >> 6, lane = tid & 63;
  int row = blockIdx.x * 4 + w;           // 0..2047 (t*32+b)
  float s = 0.f;
  for (int j = lane; j < NBN; j += 64) s += partials[(size_t)row * NBN + j];
#pragma unroll
  for (int off = 32; off > 0; off >>= 1) s += __shfl_down(s, off, 64);
  int tok = y[row + 32];                  // y[(t+1)*32 + b]
  float d = 0.f;
  for (int k = lane; k < H; k += 64)
    d += bf2f(H1P[(size_t)row * KH + k]) * Wout[(size_t)tok * H + k];
#pragma unroll
  for (int off = 32; off > 0; off >>= 1) d += __shfl_down(d, off, 64);
  __shared__ float bsum[4];
  if (lane == 0) bsum[w] = __logf(s) - (d + bout[tok]);
  __syncthreads();
  if (tid == 0) atomicAdd(out, (bsum[0] + bsum[1] + bsum[2] + bsum[3]) * (1.f / 32.f));
}

// ---------------- host ----------------
extern "C" void kernel_launch(void* const* d_in, const int* in_sizes, int n_in,
                              void* d_out, int out_size, void* d_ws, size_t ws_size,
                              hipStream_t stream) {
  const int*   x      = (const int*)d_in[0];
  const int*   y      = (const int*)d_in[1];
  const float* encemb = (const float*)d_in[2];
  const float* decemb = (const float*)d_in[3];
  const float* eWih0  = (const float*)d_in[4];
  const float* eWhh0  = (const float*)d_in[5];
  const float* ebih0  = (const float*)d_in[6];
  const float* ebhh0  = (const float*)d_in[7];
  const float* eWih1  = (const float*)d_in[8];
  const float* eWhh1  = (const float*)d_in[9];
  const float* ebih1  = (const float*)d_in[10];
  const float* ebhh1  = (const float*)d_in[11];
  const float* dWih0  = (const float*)d_in[12];
  const float* dWhh0  = (const float*)d_in[13];
  const float* dbih0  = (const float*)d_in[14];
  const float* dbhh0  = (const float*)d_in[15];
  const float* dWih1  = (const float*)d_in[16];
  const float* dWhh1  = (const float*)d_in[17];
  const float* dbih1  = (const float*)d_in[18];
  const float* dbhh1  = (const float*)d_in[19];
  const float* Wout   = (const float*)d_in[20];
  const float* bout   = (const float*)d_in[21];
  float* out = (float*)d_out;

  char* wsb = (char*)d_ws;
  size_t off = 0;
  auto alloc = [&](size_t bytes) -> void* {
    void* p = wsb + off;
    off += (bytes + 255) & ~(size_t)255;
    return p;
  };
  short* WoutP = (short*)alloc((size_t)V * KH * 2);
  short* WAe   = (short*)alloc((size_t)NB * 17408 * 2);
  short* WBe   = (short*)alloc((size_t)NB * 34816 * 2);
  short* WAd   = (short*)alloc((size_t)NB * 17408 * 2);
  short* WBd   = (short*)alloc((size_t)NB * 34816 * 2);
  short* WihPe = (short*)alloc((size_t)GP * KE * 2);
  short* WihPd = (short*)alloc((size_t)GP * KE * 2);
  float* b0e   = (float*)alloc(GP * 4);
  float* b1e   = (float*)alloc(GP * 4);
  float* b0d   = (float*)alloc(GP * 4);
  float* b1d   = (float*)alloc(GP * 4);
  float* X0e   = (float*)alloc((size_t)SEQ * GP * SB * 4);
  float* X0d   = (float*)alloc((size_t)SEQ * GP * SB * 4);
  short* h0g   = (short*)alloc((size_t)2 * 17408 * 2);
  short* h1g   = (short*)alloc((size_t)2 * 17408 * 2);
  short* H1P   = (short*)alloc((size_t)MROW * KH * 2);
  float* parts = (float*)alloc((size_t)MROW * NBN * 4);

  hipMemsetAsync(d_out, 0, sizeof(float), stream);
  hipMemsetAsync(h0g, 0, (size_t)2 * 17408 * 2, stream);
  hipMemsetAsync(h1g, 0, (size_t)2 * 17408 * 2, stream);

  k_pack_bias<<<(GP + 255) / 256, 256, 0, stream>>>(ebih0, ebhh0, ebih1, ebhh1,
                                                    dbih0, dbhh0, dbih1, dbhh1,
                                                    b0e, b1e, b0d, b1d);
  k_pack_wih<<<(GP * KE / 8 + 255) / 256, 256, 0, stream>>>(eWih0, WihPe);
  k_pack_wih<<<(GP * KE / 8 + 255) / 256, 256, 0, stream>>>(dWih0, WihPd);
  {
    int totA = NB * 2 * 17 * 64, totB = NB * 2 * 34 * 64;
    k_pack_gates<<<(totA + 255) / 256, 256, 0, stream>>>(eWhh0, eWhh0, WAe, 17);
    k_pack_gates<<<(totB + 255) / 256, 256, 0, stream>>>(eWih1, eWhh1, WBe, 34);
    k_pack_gates<<<(totA + 255) / 256, 256, 0, stream>>>(dWhh0, dWhh0, WAd, 17);
    k_pack_gates<<<(totB + 255) / 256, 256, 0, stream>>>(dWih1, dWhh1, WBd, 34);
  }
  k_pack_wout<<<(V * (KH / 8) + 255) / 256, 256, 0, stream>>>(Wout, WoutP);

  k_embproj<<<dim3(GP / 16, 32), 256, 0, stream>>>(WihPe, encemb, x, b0e, X0e);
  k_embproj<<<dim3(GP / 16, 32), 256, 0, stream>>>(WihPd, decemb, y, b0d, X0d);

  RecArgs ra{WAe, WBe, WAd, WBd, X0e, X0d, b1e, b1d, h0g, h1g, H1P};
  void* kargs[] = {&ra};
  hipLaunchCooperativeKernel((const void*)k_recur, dim3(NB), dim3(256), kargs, 0, stream);

  k_project<<<dim3(MROW / 128, NBN), 256, 0, stream>>>(H1P, WoutP, bout, parts);
  k_finish<<<MROW / 4, 256, 0, stream>>>(parts, H1P, Wout, bout, y, out);
}

// Round 2
// 1964.206 us; speedup vs baseline: 3.1238x; 3.1238x over previous
//
#include <hip/hip_runtime.h>

typedef __attribute__((ext_vector_type(8))) short short8;
typedef __attribute__((ext_vector_type(4))) float f32x4;
typedef unsigned long long ull;

constexpr int H    = 516;    // hidden
constexpr int GP   = 2080;   // padded gate cols (65*32), permuted chat = 4*u+g
constexpr int KH   = 544;    // padded hidden K (17*32)
constexpr int KE   = 256;    // embedding dim
constexpr int NB   = 65;     // recurrence blocks (8 units each -> 520 padded units)
constexpr int SB   = 32;     // batch
constexpr int SEQ  = 64;
constexpr int MROW = 2048;   // SEQ*SB
constexpr int V    = 32000;
constexpr int NBN  = 250;    // V/128

__device__ __forceinline__ float bf2f(short s) {
  unsigned u = ((unsigned)(unsigned short)s) << 16;
  float f; __builtin_memcpy(&f, &u, 4); return f;
}
__device__ __forceinline__ short f2bf(float f) {
  unsigned u; __builtin_memcpy(&u, &f, 4);
  u += 0x7fffu + ((u >> 16) & 1u);
  return (short)(u >> 16);
}
__device__ __forceinline__ float sigm(float x){ return 1.f/(1.f+__expf(-x)); }
__device__ __forceinline__ float tanh_(float x){ float e=__expf(-2.f*x); return (1.f-e)/(1.f+e); }

// coherent (MALL) 16B load as two 8B relaxed agent-scope atomic loads
__device__ __forceinline__ short8 ld_coh16(const ull* p) {
  ull a = __hip_atomic_load(p,     __ATOMIC_RELAXED, __HIP_MEMORY_SCOPE_AGENT);
  ull b = __hip_atomic_load(p + 1, __ATOMIC_RELAXED, __HIP_MEMORY_SCOPE_AGENT);
  union { ull u[2]; short8 s; } cv;
  cv.u[0] = a; cv.u[1] = b;
  return cv.s;
}

// ---------------- pack kernels ----------------
__global__ void k_pack_gates(const float* __restrict__ W1, const float* __restrict__ W2,
                             short* __restrict__ dst, int ksteps) {
  int gid = blockIdx.x * 256 + threadIdx.x;
  int total = NB * 2 * ksteps * 64;
  if (gid >= total) return;
  int lane = gid & 63;
  int rest = gid >> 6;
  int ks = rest % ksteps; rest /= ksteps;
  int nt = rest & 1; int bid = rest >> 1;
  int chat = bid * 32 + nt * 16 + (lane & 15);
  int u = chat >> 2, g = chat & 3;
  int kb = ks * 32 + (lane >> 4) * 8;
  short8 v;
#pragma unroll
  for (int j = 0; j < 8; ++j) {
    int k = kb + j;
    const float* src = W1; int kk = k;
    if (k >= KH) { src = W2; kk = k - KH; }
    float f = 0.f;
    if (u < H && kk < H) f = src[(size_t)(g * H + u) * H + kk];
    v[j] = f2bf(f);
  }
  *(short8*)(dst + (size_t)gid * 8) = v;
}

__global__ void k_pack_wout(const float* __restrict__ Wout, short* __restrict__ dst) {
  int gid = blockIdx.x * 256 + threadIdx.x;          // group of 8
  if (gid >= V * (KH / 8)) return;
  int row = gid / (KH / 8);
  int kb = (gid % (KH / 8)) * 8;
  short8 v;
#pragma unroll
  for (int j = 0; j < 8; ++j) {
    int k = kb + j;
    v[j] = f2bf(k < H ? Wout[(size_t)row * H + k] : 0.f);
  }
  *(short8*)(dst + (size_t)gid * 8) = v;
}

__global__ void k_pack_wih(const float* __restrict__ Wih0, short* __restrict__ dst) {
  int gid = blockIdx.x * 256 + threadIdx.x;          // group of 8
  if (gid >= GP * (KE / 8)) return;
  int chat = gid / (KE / 8);
  int kb = (gid % (KE / 8)) * 8;
  int u = chat >> 2, g = chat & 3;
  short8 v;
#pragma unroll
  for (int j = 0; j < 8; ++j)
    v[j] = f2bf(u < H ? Wih0[(size_t)(g * H + u) * KE + kb + j] : 0.f);
  *(short8*)(dst + (size_t)gid * 8) = v;
}

__global__ void k_pack_bias(const float* ebih0, const float* ebhh0, const float* ebih1, const float* ebhh1,
                            const float* dbih0, const float* dbhh0, const float* dbih1, const float* dbhh1,
                            float* b0e, float* b1e, float* b0d, float* b1d) {
  int chat = blockIdx.x * 256 + threadIdx.x;
  if (chat >= GP) return;
  int u = chat >> 2, g = chat & 3, n = g * H + u;
  bool ok = (u < H);
  b0e[chat] = ok ? ebih0[n] + ebhh0[n] : 0.f;
  b1e[chat] = ok ? ebih1[n] + ebhh1[n] : 0.f;
  b0d[chat] = ok ? dbih0[n] + dbhh0[n] : 0.f;
  b1d[chat] = ok ? dbih1[n] + dbhh1[n] : 0.f;
}

// ---------------- batched input projection ----------------
__global__ void __launch_bounds__(256) k_embproj(const short* __restrict__ WihP,
                                                 const float* __restrict__ emb,
                                                 const int* __restrict__ toks,
                                                 const float* __restrict__ b0P,
                                                 float* __restrict__ X0P) {
  int tid = threadIdx.x, w = tid >> 6, lane = tid & 63, q = lane >> 4, col = lane & 15;
  int mt = blockIdx.x;                 // 0..129
  int ntile = blockIdx.y * 4 + w;      // 0..127
  int tb = ntile * 16 + col;
  int tok = toks[tb];
  const short* Ap = WihP + (size_t)(mt * 16 + col) * KE + q * 8;
  const float* Bp = emb + (size_t)tok * KE + q * 8;
  f32x4 acc = {0.f, 0.f, 0.f, 0.f};
#pragma unroll
  for (int ks = 0; ks < 8; ++ks) {
    short8 a = *(const short8*)(Ap + ks * 32);
    const f32x4* b4 = (const f32x4*)(Bp + ks * 32);
    f32x4 b0v = b4[0], b1v = b4[1];
    short8 bb;
    bb[0]=f2bf(b0v[0]); bb[1]=f2bf(b0v[1]); bb[2]=f2bf(b0v[2]); bb[3]=f2bf(b0v[3]);
    bb[4]=f2bf(b1v[0]); bb[5]=f2bf(b1v[1]); bb[6]=f2bf(b1v[2]); bb[7]=f2bf(b1v[3]);
    acc = __builtin_amdgcn_mfma_f32_16x16x32_bf16(a, bb, acc, 0, 0, 0);
  }
  int chat0 = mt * 16 + q * 4;
  f32x4 bias = *(const f32x4*)(b0P + chat0);
  int t = tb >> 5, b = tb & 31;
  float* dst = X0P + ((size_t)t * GP) * 32 + b;
#pragma unroll
  for (int r = 0; r < 4; ++r)
    dst[(size_t)(chat0 + r) * 32] = acc[r] + bias[r];
}

// ---------------- cooperative recurrence ----------------
// One grid barrier per iteration; layer 1 pipelined one timestep behind layer 0.
// h-state exchanged via MALL-coherent relaxed agent atomics (no L2 fences).
struct RecArgs {
  const short *WAe, *WBe, *WAd, *WBd;
  const float *X0e, *X0d, *b1e, *b1d;
  short *h0g, *h1g, *H1P;   // h0g/h1g: double-buffered [2][32][KH] bf16
  unsigned *bar;            // [0]=cnt, [64]=gen
};

__global__ void __launch_bounds__(256) k_recur(RecArgs A) {
  const int tid = threadIdx.x, lane = tid & 63, w = tid >> 6;
  const int q = lane >> 4, col = lane & 15;
  const int mt = w >> 1, nt = w & 1;
  const int bid = blockIdx.x;
  const int chat_l = nt * 16 + col, chat = bid * 32 + chat_l;
  const int am = mt * 16 + col;               // A-fragment row (batch index)
  __shared__ float c0[32][8], c1[32][8];
  __shared__ float gbuf0[32][33], gbuf1[32][33];
  const int cb = tid >> 2, up = tid & 3;      // cell threads: tid<128, 2 units each
  if (tid < 128) {
    c0[cb][up * 2] = 0.f; c0[cb][up * 2 + 1] = 0.f;
    c1[cb][up * 2] = 0.f; c1[cb][up * 2 + 1] = 0.f;
  }
  unsigned* cnt = A.bar;
  unsigned* gen = A.bar + 64;
  const int fragoff = (am * KH + q * 8) / 4;  // in ull units

  for (int i = 0; i < 129; ++i) {
    const int rp = (i + 1) & 1, wp = i & 1;

    // ---- layer 0: t = i ----
    if (i < 128) {
      const int ph = i >> 6, t = i & 63;
      const short* WA = (ph ? A.WAd : A.WAe) + (size_t)bid * 17408 + (size_t)(nt * 17 * 64 + lane) * 8;
      const float* X0 = ph ? A.X0d : A.X0e;
      const ull* Ar = (const ull*)(A.h0g + rp * 17408) + fragoff;
      short8 afs[17];
#pragma unroll
      for (int ks = 0; ks < 17; ++ks) afs[ks] = ld_coh16(Ar + ks * 8);
      f32x4 acc = {0.f, 0.f, 0.f, 0.f};
#pragma unroll
      for (int ks = 0; ks < 17; ++ks) {
        short8 bf = *(const short8*)(WA + ks * 512);
        acc = __builtin_amdgcn_mfma_f32_16x16x32_bf16(afs[ks], bf, acc, 0, 0, 0);
      }
      f32x4 xv = *(const f32x4*)(X0 + ((size_t)t * GP + chat) * 32 + mt * 16 + q * 4);
#pragma unroll
      for (int r = 0; r < 4; ++r) gbuf0[mt * 16 + q * 4 + r][chat_l] = acc[r] + xv[r];
    }
    __syncthreads();
    if (i < 128 && tid < 128) {
      unsigned hv = 0;
#pragma unroll
      for (int s = 0; s < 2; ++s) {
        int base = up * 8 + s * 4;
        float gi = gbuf0[cb][base + 0], gf = gbuf0[cb][base + 1];
        float gg = gbuf0[cb][base + 2], go = gbuf0[cb][base + 3];
        float c = c0[cb][up * 2 + s];
        float cn = sigm(gf) * c + sigm(gi) * tanh_(gg);
        float hn = sigm(go) * tanh_(cn);
        c0[cb][up * 2 + s] = cn;
        hv |= ((unsigned)(unsigned short)f2bf(hn)) << (16 * s);
      }
      __hip_atomic_store((unsigned*)(A.h0g + wp * 17408) + cb * 272 + bid * 4 + up, hv,
                         __ATOMIC_RELAXED, __HIP_MEMORY_SCOPE_AGENT);
    }

    // ---- layer 1: t = i-1 ----
    if (i >= 1) {
      const int i1 = i - 1, ph = i1 >> 6;
      const short* WB = (ph ? A.WBd : A.WBe) + (size_t)bid * 34816 + (size_t)(nt * 34 * 64 + lane) * 8;
      const float* b1 = ph ? A.b1d : A.b1e;
      const ull* Ar0 = (const ull*)(A.h0g + rp * 17408) + fragoff;
      const ull* Ar1 = (const ull*)(A.h1g + rp * 17408) + fragoff;
      short8 a0[17], a1[17];
#pragma unroll
      for (int ks = 0; ks < 17; ++ks) a0[ks] = ld_coh16(Ar0 + ks * 8);
#pragma unroll
      for (int ks = 0; ks < 17; ++ks) a1[ks] = ld_coh16(Ar1 + ks * 8);
      f32x4 acc = {0.f, 0.f, 0.f, 0.f};
#pragma unroll
      for (int ks = 0; ks < 17; ++ks) {
        short8 bf = *(const short8*)(WB + ks * 512);
        acc = __builtin_amdgcn_mfma_f32_16x16x32_bf16(a0[ks], bf, acc, 0, 0, 0);
      }
#pragma unroll
      for (int ks = 0; ks < 17; ++ks) {
        short8 bf = *(const short8*)(WB + (size_t)(17 + ks) * 512);
        acc = __builtin_amdgcn_mfma_f32_16x16x32_bf16(a1[ks], bf, acc, 0, 0, 0);
      }
      float bias1 = b1[chat];
#pragma unroll
      for (int r = 0; r < 4; ++r) gbuf1[mt * 16 + q * 4 + r][chat_l] = acc[r] + bias1;
    }
    __syncthreads();
    if (i >= 1 && tid < 128) {
      const int i1 = i - 1;
      unsigned hv = 0;
#pragma unroll
      for (int s = 0; s < 2; ++s) {
        int base = up * 8 + s * 4;
        float gi = gbuf1[cb][base + 0], gf = gbuf1[cb][base + 1];
        float gg = gbuf1[cb][base + 2], go = gbuf1[cb][base + 3];
        float c = c1[cb][up * 2 + s];
        float cn = sigm(gf) * c + sigm(gi) * tanh_(gg);
        float hn = sigm(go) * tanh_(cn);
        c1[cb][up * 2 + s] = cn;
        hv |= ((unsigned)(unsigned short)f2bf(hn)) << (16 * s);
      }
      __hip_atomic_store((unsigned*)(A.h1g + wp * 17408) + cb * 272 + bid * 4 + up, hv,
                         __ATOMIC_RELAXED, __HIP_MEMORY_SCOPE_AGENT);
      if (i1 >= 64)
        *((unsigned*)(A.H1P) + (size_t)((i1 - 64) * SB + cb) * 272 + bid * 4 + up) = hv;
    }

    // ---- grid barrier (fence-free, MALL-coherent) ----
    asm volatile("s_waitcnt vmcnt(0)" ::: "memory");
    __syncthreads();
    if (tid == 0) {
      unsigned target = (unsigned)(i + 1);
      unsigned old = __hip_atomic_fetch_add(cnt, 1u, __ATOMIC_RELAXED, __HIP_MEMORY_SCOPE_AGENT);
      if (old == (unsigned)NB * target - 1u) {
        __hip_atomic_store(gen, target, __ATOMIC_RELAXED, __HIP_MEMORY_SCOPE_AGENT);
      } else {
        while (__hip_atomic_load(gen, __ATOMIC_RELAXED, __HIP_MEMORY_SCOPE_AGENT) < target) {}
      }
    }
    __syncthreads();
  }
}

// ---------------- projection GEMM + streamed sum-exp ----------------
__global__ void __launch_bounds__(256) k_project(const short* __restrict__ H1P,
                                                 const short* __restrict__ WoutP,
                                                 const float* __restrict__ bout,
                                                 float* __restrict__ partials) {
  int bM = blockIdx.x, bN = blockIdx.y;
  int tid = threadIdx.x, w = tid >> 6, lane = tid & 63, q = lane >> 4, col = lane & 15;
  int wm = w >> 1, wn = w & 1;
  __shared__ __align__(16) short As[128 * 32];
  __shared__ __align__(16) short Bs[128 * 32];
  __shared__ float sred[128][2];
  f32x4 acc[4][4];
#pragma unroll
  for (int mi = 0; mi < 4; ++mi)
#pragma unroll
    for (int ni = 0; ni < 4; ++ni) acc[mi][ni] = (f32x4){0.f, 0.f, 0.f, 0.f};

  for (int ks = 0; ks < 17; ++ks) {
#pragma unroll
    for (int i = 0; i < 2; ++i) {
      int chunk = tid * 2 + i;               // 0..511
      int row = chunk >> 2, ch = chunk & 3;
      ((short8*)As)[chunk] = *(const short8*)(H1P  + (size_t)(bM * 128 + row) * KH + ks * 32 + ch * 8);
      ((short8*)Bs)[chunk] = *(const short8*)(WoutP + (size_t)(bN * 128 + row) * KH + ks * 32 + ch * 8);
    }
    __syncthreads();
    short8 af[4], bf[4];
#pragma unroll
    for (int mi = 0; mi < 4; ++mi) af[mi] = *(const short8*)(As + (wm * 64 + mi * 16 + col) * 32 + q * 8);
#pragma unroll
    for (int ni = 0; ni < 4; ++ni) bf[ni] = *(const short8*)(Bs + (wn * 64 + ni * 16 + col) * 32 + q * 8);
#pragma unroll
    for (int mi = 0; mi < 4; ++mi)
#pragma unroll
      for (int ni = 0; ni < 4; ++ni)
        acc[mi][ni] = __builtin_amdgcn_mfma_f32_16x16x32_bf16(af[mi], bf[ni], acc[mi][ni], 0, 0, 0);
    __syncthreads();
  }
  float bias[4];
#pragma unroll
  for (int ni = 0; ni < 4; ++ni) bias[ni] = bout[bN * 128 + wn * 64 + ni * 16 + col];
#pragma unroll
  for (int mi = 0; mi < 4; ++mi) {
#pragma unroll
    for (int r = 0; r < 4; ++r) {
      float s = 0.f;
#pragma unroll
      for (int ni = 0; ni < 4; ++ni) s += __expf(acc[mi][ni][r] + bias[ni]);
      s += __shfl_xor(s, 1, 64); s += __shfl_xor(s, 2, 64);
      s += __shfl_xor(s, 4, 64); s += __shfl_xor(s, 8, 64);
      if (col == 0) sred[wm * 64 + mi * 16 + q * 4 + r][wn] = s;
    }
  }
  __syncthreads();
  if (tid < 128)
    partials[(size_t)(bM * 128 + tid) * NBN + bN] = sred[tid][0] + sred[tid][1];
}

// ---------------- finish: lse + target logit + loss ----------------
__global__ void __launch_bounds__(256) k_finish(const float* __restrict__ partials,
                                                const short* __restrict__ H1P,
                                                const float* __restrict__ Wout,
                                                const float* __restrict__ bout,
                                                const int* __restrict__ y,
                                                float* __restrict__ out) {
  int tid = threadIdx.x, w = tid >> 6, lane = tid & 63;
  int row = blockIdx.x * 4 + w;           // 0..2047 (t*32+b)
  float s = 0.f;
  for (int j = lane; j < NBN; j += 64) s += partials[(size_t)row * NBN + j];
#pragma unroll
  for (int off = 32; off > 0; off >>= 1) s += __shfl_down(s, off, 64);
  int tok = y[row + 32];                  // y[(t+1)*32 + b]
  float d = 0.f;
  for (int k = lane; k < H; k += 64)
    d += bf2f(H1P[(size_t)row * KH + k]) * Wout[(size_t)tok * H + k];
#pragma unroll
  for (int off = 32; off > 0; off >>= 1) d += __shfl_down(d, off, 64);
  __shared__ float bsum[4];
  if (lane == 0) bsum[w] = __logf(s) - (d + bout[tok]);
  __syncthreads();
  if (tid == 0) atomicAdd(out, (bsum[0] + bsum[1] + bsum[2] + bsum[3]) * (1.f / 32.f));
}

// ---------------- host ----------------
extern "C" void kernel_launch(void* const* d_in, const int* in_sizes, int n_in,
                              void* d_out, int out_size, void* d_ws, size_t ws_size,
                              hipStream_t stream) {
  const int*   x      = (const int*)d_in[0];
  const int*   y      = (const int*)d_in[1];
  const float* encemb = (const float*)d_in[2];
  const float* decemb = (const float*)d_in[3];
  const float* eWih0  = (const float*)d_in[4];
  const float* eWhh0  = (const float*)d_in[5];
  const float* ebih0  = (const float*)d_in[6];
  const float* ebhh0  = (const float*)d_in[7];
  const float* eWih1  = (const float*)d_in[8];
  const float* eWhh1  = (const float*)d_in[9];
  const float* ebih1  = (const float*)d_in[10];
  const float* ebhh1  = (const float*)d_in[11];
  const float* dWih0  = (const float*)d_in[12];
  const float* dWhh0  = (const float*)d_in[13];
  const float* dbih0  = (const float*)d_in[14];
  const float* dbhh0  = (const float*)d_in[15];
  const float* dWih1  = (const float*)d_in[16];
  const float* dWhh1  = (const float*)d_in[17];
  const float* dbih1  = (const float*)d_in[18];
  const float* dbhh1  = (const float*)d_in[19];
  const float* Wout   = (const float*)d_in[20];
  const float* bout   = (const float*)d_in[21];
  float* out = (float*)d_out;

  char* wsb = (char*)d_ws;
  size_t off = 0;
  auto alloc = [&](size_t bytes) -> void* {
    void* p = wsb + off;
    off += (bytes + 255) & ~(size_t)255;
    return p;
  };
  short* WoutP = (short*)alloc((size_t)V * KH * 2);
  short* WAe   = (short*)alloc((size_t)NB * 17408 * 2);
  short* WBe   = (short*)alloc((size_t)NB * 34816 * 2);
  short* WAd   = (short*)alloc((size_t)NB * 17408 * 2);
  short* WBd   = (short*)alloc((size_t)NB * 34816 * 2);
  short* WihPe = (short*)alloc((size_t)GP * KE * 2);
  short* WihPd = (short*)alloc((size_t)GP * KE * 2);
  float* b0e   = (float*)alloc(GP * 4);
  float* b1e   = (float*)alloc(GP * 4);
  float* b0d   = (float*)alloc(GP * 4);
  float* b1d   = (float*)alloc(GP * 4);
  float* X0e   = (float*)alloc((size_t)SEQ * GP * SB * 4);
  float* X0d   = (float*)alloc((size_t)SEQ * GP * SB * 4);
  short* h0g   = (short*)alloc((size_t)2 * 17408 * 2);
  short* h1g   = (short*)alloc((size_t)2 * 17408 * 2);
  short* H1P   = (short*)alloc((size_t)MROW * KH * 2);
  float* parts = (float*)alloc((size_t)MROW * NBN * 4);
  unsigned* bar = (unsigned*)alloc(256 * 4);

  hipMemsetAsync(d_out, 0, sizeof(float), stream);
  hipMemsetAsync(h0g, 0, (size_t)2 * 17408 * 2, stream);
  hipMemsetAsync(h1g, 0, (size_t)2 * 17408 * 2, stream);
  hipMemsetAsync(bar, 0, 256 * 4, stream);

  k_pack_bias<<<(GP + 255) / 256, 256, 0, stream>>>(ebih0, ebhh0, ebih1, ebhh1,
                                                    dbih0, dbhh0, dbih1, dbhh1,
                                                    b0e, b1e, b0d, b1d);
  k_pack_wih<<<(GP * KE / 8 + 255) / 256, 256, 0, stream>>>(eWih0, WihPe);
  k_pack_wih<<<(GP * KE / 8 + 255) / 256, 256, 0, stream>>>(dWih0, WihPd);
  {
    int totA = NB * 2 * 17 * 64, totB = NB * 2 * 34 * 64;
    k_pack_gates<<<(totA + 255) / 256, 256, 0, stream>>>(eWhh0, eWhh0, WAe, 17);
    k_pack_gates<<<(totB + 255) / 256, 256, 0, stream>>>(eWih1, eWhh1, WBe, 34);
    k_pack_gates<<<(totA + 255) / 256, 256, 0, stream>>>(dWhh0, dWhh0, WAd, 17);
    k_pack_gates<<<(totB + 255) / 256, 256, 0, stream>>>(dWih1, dWhh1, WBd, 34);
  }
  k_pack_wout<<<(V * (KH / 8) + 255) / 256, 256, 0, stream>>>(Wout, WoutP);

  k_embproj<<<dim3(GP / 16, 32), 256, 0, stream>>>(WihPe, encemb, x, b0e, X0e);
  k_embproj<<<dim3(GP / 16, 32), 256, 0, stream>>>(WihPd, decemb, y, b0d, X0d);

  RecArgs ra{WAe, WBe, WAd, WBd, X0e, X0d, b1e, b1d, h0g, h1g, H1P, bar};
  void* kargs[] = {&ra};
  hipLaunchCooperativeKernel((const void*)k_recur, dim3(NB), dim3(256), kargs, 0, stream);

  k_project<<<dim3(MROW / 128, NBN), 256, 0, stream>>>(H1P, WoutP, bout, parts);
  k_finish<<<MROW / 4, 256, 0, stream>>>(parts, H1P, Wout, bout, y, out);
}

// Round 3
// 1182.529 us; speedup vs baseline: 5.1887x; 1.6610x over previous
//
#include <hip/hip_runtime.h>

typedef __attribute__((ext_vector_type(8))) short short8;
typedef __attribute__((ext_vector_type(4))) float f32x4;
typedef unsigned long long ull;

constexpr int H    = 516;    // hidden
constexpr int GP   = 2080;   // padded gate cols (65*32), permuted chat = 4*u+g
constexpr int KH   = 544;    // padded hidden K (17*32)
constexpr int KE   = 256;    // embedding dim
constexpr int NB   = 65;     // recurrence blocks (8 units each -> 520 padded units)
constexpr int SB   = 32;     // batch
constexpr int SEQ  = 64;
constexpr int MROW = 2048;   // SEQ*SB
constexpr int V    = 32000;
constexpr int NBN  = 250;    // V/128
constexpr int HSROW = 552;   // padded LDS row stride (shorts) -> conflict-free b128

__device__ __forceinline__ float bf2f(short s) {
  unsigned u = ((unsigned)(unsigned short)s) << 16;
  float f; __builtin_memcpy(&f, &u, 4); return f;
}
__device__ __forceinline__ short f2bf(float f) {
  unsigned u; __builtin_memcpy(&u, &f, 4);
  u += 0x7fffu + ((u >> 16) & 1u);
  return (short)(u >> 16);
}
__device__ __forceinline__ float sigm(float x){ return 1.f/(1.f+__expf(-x)); }
__device__ __forceinline__ float tanh_(float x){ float e=__expf(-2.f*x); return (1.f-e)/(1.f+e); }

// ---------------- pack kernels ----------------
__global__ void k_pack_gates(const float* __restrict__ W1, const float* __restrict__ W2,
                             short* __restrict__ dst, int ksteps) {
  int gid = blockIdx.x * 256 + threadIdx.x;
  int total = NB * 2 * ksteps * 64;
  if (gid >= total) return;
  int lane = gid & 63;
  int rest = gid >> 6;
  int ks = rest % ksteps; rest /= ksteps;
  int nt = rest & 1; int bid = rest >> 1;
  int chat = bid * 32 + nt * 16 + (lane & 15);
  int u = chat >> 2, g = chat & 3;
  int kb = ks * 32 + (lane >> 4) * 8;
  short8 v;
#pragma unroll
  for (int j = 0; j < 8; ++j) {
    int k = kb + j;
    const float* src = W1; int kk = k;
    if (k >= KH) { src = W2; kk = k - KH; }
    float f = 0.f;
    if (u < H && kk < H) f = src[(size_t)(g * H + u) * H + kk];
    v[j] = f2bf(f);
  }
  *(short8*)(dst + (size_t)gid * 8) = v;
}

__global__ void k_pack_wout(const float* __restrict__ Wout, short* __restrict__ dst) {
  int gid = blockIdx.x * 256 + threadIdx.x;          // group of 8
  if (gid >= V * (KH / 8)) return;
  int row = gid / (KH / 8);
  int kb = (gid % (KH / 8)) * 8;
  short8 v;
#pragma unroll
  for (int j = 0; j < 8; ++j) {
    int k = kb + j;
    v[j] = f2bf(k < H ? Wout[(size_t)row * H + k] : 0.f);
  }
  *(short8*)(dst + (size_t)gid * 8) = v;
}

__global__ void k_pack_wih(const float* __restrict__ Wih0, short* __restrict__ dst) {
  int gid = blockIdx.x * 256 + threadIdx.x;          // group of 8
  if (gid >= GP * (KE / 8)) return;
  int chat = gid / (KE / 8);
  int kb = (gid % (KE / 8)) * 8;
  int u = chat >> 2, g = chat & 3;
  short8 v;
#pragma unroll
  for (int j = 0; j < 8; ++j)
    v[j] = f2bf(u < H ? Wih0[(size_t)(g * H + u) * KE + kb + j] : 0.f);
  *(short8*)(dst + (size_t)gid * 8) = v;
}

__global__ void k_pack_bias(const float* ebih0, const float* ebhh0, const float* ebih1, const float* ebhh1,
                            const float* dbih0, const float* dbhh0, const float* dbih1, const float* dbhh1,
                            float* b0e, float* b1e, float* b0d, float* b1d) {
  int chat = blockIdx.x * 256 + threadIdx.x;
  if (chat >= GP) return;
  int u = chat >> 2, g = chat & 3, n = g * H + u;
  bool ok = (u < H);
  b0e[chat] = ok ? ebih0[n] + ebhh0[n] : 0.f;
  b1e[chat] = ok ? ebih1[n] + ebhh1[n] : 0.f;
  b0d[chat] = ok ? dbih0[n] + dbhh0[n] : 0.f;
  b1d[chat] = ok ? dbih1[n] + dbhh1[n] : 0.f;
}

// ---------------- batched input projection ----------------
__global__ void __launch_bounds__(256) k_embproj(const short* __restrict__ WihP,
                                                 const float* __restrict__ emb,
                                                 const int* __restrict__ toks,
                                                 const float* __restrict__ b0P,
                                                 float* __restrict__ X0P) {
  int tid = threadIdx.x, w = tid >> 6, lane = tid & 63, q = lane >> 4, col = lane & 15;
  int mt = blockIdx.x;                 // 0..129
  int ntile = blockIdx.y * 4 + w;      // 0..127
  int tb = ntile * 16 + col;
  int tok = toks[tb];
  const short* Ap = WihP + (size_t)(mt * 16 + col) * KE + q * 8;
  const float* Bp = emb + (size_t)tok * KE + q * 8;
  f32x4 acc = {0.f, 0.f, 0.f, 0.f};
#pragma unroll
  for (int ks = 0; ks < 8; ++ks) {
    short8 a = *(const short8*)(Ap + ks * 32);
    const f32x4* b4 = (const f32x4*)(Bp + ks * 32);
    f32x4 b0v = b4[0], b1v = b4[1];
    short8 bb;
    bb[0]=f2bf(b0v[0]); bb[1]=f2bf(b0v[1]); bb[2]=f2bf(b0v[2]); bb[3]=f2bf(b0v[3]);
    bb[4]=f2bf(b1v[0]); bb[5]=f2bf(b1v[1]); bb[6]=f2bf(b1v[2]); bb[7]=f2bf(b1v[3]);
    acc = __builtin_amdgcn_mfma_f32_16x16x32_bf16(a, bb, acc, 0, 0, 0);
  }
  int chat0 = mt * 16 + q * 4;
  f32x4 bias = *(const f32x4*)(b0P + chat0);
  int t = tb >> 5, b = tb & 31;
  float* dst = X0P + ((size_t)t * GP) * 32 + b;
#pragma unroll
  for (int r = 0; r < 4; ++r)
    dst[(size_t)(chat0 + r) * 32] = acc[r] + bias[r];
}

// ---------------- cooperative recurrence ----------------
// h-state: hst[parity][layer][32][544] bf16 (global, exchanged via MALL).
// Per iter: batched cache-bypass stage -> LDS; both layers' MFMA from LDS;
// split cell updates; 64B-padded flag-array barrier (no serialized RMW).
struct RecArgs {
  const short *WAe, *WBe, *WAd, *WBd;
  const float *X0e, *X0d, *b1e, *b1d;
  short *hst, *H1P;
  unsigned *bar;            // 65 flags, stride 16 u32 (64B)
};

__global__ void __launch_bounds__(256) k_recur(RecArgs A) {
  const int tid = threadIdx.x, lane = tid & 63, w = tid >> 6;
  const int q = lane >> 4, col = lane & 15;
  const int mt = w >> 1, nt = w & 1;
  const int bid = blockIdx.x;
  const int chat_l = nt * 16 + col, chat = bid * 32 + chat_l;
  const int am = mt * 16 + col;               // A-fragment row (batch index)
  __shared__ __align__(16) short hs[2][32][HSROW];   // staged h0,h1 (read parity)
  __shared__ float c0[32][8], c1[32][8];
  __shared__ float gbuf0[32][33], gbuf1[32][33];
  const int tl = tid & 127, cb = tl >> 2, up = tl & 3;
  if (tid < 128) { c0[cb][up * 2] = 0.f; c0[cb][up * 2 + 1] = 0.f; }
  else           { c1[cb][up * 2] = 0.f; c1[cb][up * 2 + 1] = 0.f; }

  // precompute LDS staging offsets (shorts): chunk c = tid + 256*j
  short* hsflat = &hs[0][0][0];
  int loff[17];
#pragma unroll
  for (int j = 0; j < 17; ++j) {
    int c = tid + 256 * j;
    int L = (c >= 2176) ? 1 : 0;
    int cc = c - L * 2176;
    int row = cc / 68, kc = cc - row * 68;
    loff[j] = (L * 32 + row) * HSROW + kc * 8;
  }

  for (int i = 0; i < 129; ++i) {
    const int rp = (i + 1) & 1, wp = i & 1;

    // ---- stage h[rp] (both layers) into LDS: batched bypassing loads ----
    const char* gsrc = (const char*)A.hst + (size_t)rp * 69632 + tid * 16;
    short8 tmp[17];
#pragma unroll
    for (int j = 0; j < 17; ++j)
      asm volatile("global_load_dwordx4 %0, %1, off sc0 sc1"
                   : "=v"(tmp[j]) : "v"(gsrc + j * 4096) : "memory");
    asm volatile("s_waitcnt vmcnt(0)" ::: "memory");
#pragma unroll
    for (int j = 0; j < 17; ++j)
      *(short8*)(hsflat + loff[j]) = tmp[j];
    __syncthreads();

    // ---- both layers' gate GEMMs from LDS ----
    const int ph0 = (i < 128) ? (i >> 6) : 1;
    const int i1 = i - 1;
    const int ph1 = (i >= 1) ? (i1 >> 6) : 0;
    const short* WA = (ph0 ? A.WAd : A.WAe) + (size_t)bid * 17408 + (size_t)(nt * 17 * 64 + lane) * 8;
    const short* WB = (ph1 ? A.WBd : A.WBe) + (size_t)bid * 34816 + (size_t)(nt * 34 * 64 + lane) * 8;
    f32x4 acc0 = {0.f, 0.f, 0.f, 0.f}, acc1 = {0.f, 0.f, 0.f, 0.f};
#pragma unroll
    for (int ks = 0; ks < 17; ++ks) {
      short8 a0 = *(const short8*)&hs[0][am][ks * 32 + q * 8];
      short8 a1 = *(const short8*)&hs[1][am][ks * 32 + q * 8];
      short8 w0 = *(const short8*)(WA + ks * 512);
      short8 w1 = *(const short8*)(WB + ks * 512);
      short8 w2 = *(const short8*)(WB + (size_t)(17 + ks) * 512);
      acc0 = __builtin_amdgcn_mfma_f32_16x16x32_bf16(a0, w0, acc0, 0, 0, 0);
      acc1 = __builtin_amdgcn_mfma_f32_16x16x32_bf16(a0, w1, acc1, 0, 0, 0);
      acc1 = __builtin_amdgcn_mfma_f32_16x16x32_bf16(a1, w2, acc1, 0, 0, 0);
    }
    {
      const float* X0 = ph0 ? A.X0d : A.X0e;
      const int t0 = i & 63;
      f32x4 xv = *(const f32x4*)(X0 + ((size_t)t0 * GP + chat) * 32 + mt * 16 + q * 4);
      const float* b1 = ph1 ? A.b1d : A.b1e;
      float b1v = b1[chat];
#pragma unroll
      for (int r = 0; r < 4; ++r) {
        gbuf0[mt * 16 + q * 4 + r][chat_l] = acc0[r] + xv[r];
        gbuf1[mt * 16 + q * 4 + r][chat_l] = acc1[r] + b1v;
      }
    }
    __syncthreads();

    // ---- cell updates: L0 on tid<128 (t=i), L1 on tid>=128 (t=i-1) ----
    if (tid < 128) {
      if (i < 128) {
        unsigned hv = 0;
#pragma unroll
        for (int s = 0; s < 2; ++s) {
          int base = up * 8 + s * 4;
          float gi = gbuf0[cb][base + 0], gf = gbuf0[cb][base + 1];
          float gg = gbuf0[cb][base + 2], go = gbuf0[cb][base + 3];
          float c = c0[cb][up * 2 + s];
          float cn = sigm(gf) * c + sigm(gi) * tanh_(gg);
          float hn = sigm(go) * tanh_(cn);
          c0[cb][up * 2 + s] = cn;
          hv |= ((unsigned)(unsigned short)f2bf(hn)) << (16 * s);
        }
        __hip_atomic_store((unsigned*)A.hst + wp * 17408 + cb * 272 + bid * 4 + up, hv,
                           __ATOMIC_RELAXED, __HIP_MEMORY_SCOPE_AGENT);
      }
    } else {
      if (i >= 1) {
        unsigned hv = 0;
#pragma unroll
        for (int s = 0; s < 2; ++s) {
          int base = up * 8 + s * 4;
          float gi = gbuf1[cb][base + 0], gf = gbuf1[cb][base + 1];
          float gg = gbuf1[cb][base + 2], go = gbuf1[cb][base + 3];
          float c = c1[cb][up * 2 + s];
          float cn = sigm(gf) * c + sigm(gi) * tanh_(gg);
          float hn = sigm(go) * tanh_(cn);
          c1[cb][up * 2 + s] = cn;
          hv |= ((unsigned)(unsigned short)f2bf(hn)) << (16 * s);
        }
        __hip_atomic_store((unsigned*)A.hst + wp * 17408 + 8704 + cb * 272 + bid * 4 + up, hv,
                           __ATOMIC_RELAXED, __HIP_MEMORY_SCOPE_AGENT);
        if (i1 >= 64)
          *((unsigned*)A.H1P + (size_t)((i1 - 64) * SB + cb) * 272 + bid * 4 + up) = hv;
      }
    }

    // ---- flag-array barrier ----
    if (i < 128) {
      asm volatile("s_waitcnt vmcnt(0)" ::: "memory");
      __syncthreads();
      if (tid == 0)
        __hip_atomic_store(A.bar + bid * 16, (unsigned)(i + 1),
                           __ATOMIC_RELAXED, __HIP_MEMORY_SCOPE_AGENT);
      if (tid < 64) {
        const unsigned tgt = (unsigned)(i + 1);
        unsigned* p1 = A.bar + lane * 16;
        unsigned* p2 = A.bar + (lane + 1) * 16;
        while (true) {
          unsigned a = __hip_atomic_load(p1, __ATOMIC_RELAXED, __HIP_MEMORY_SCOPE_AGENT);
          unsigned b = __hip_atomic_load(p2, __ATOMIC_RELAXED, __HIP_MEMORY_SCOPE_AGENT);
          if (__all((a >= tgt) && (b >= tgt))) break;
        }
      }
      __syncthreads();
    }
  }
}

// ---------------- projection GEMM + streamed sum-exp ----------------
__global__ void __launch_bounds__(256) k_project(const short* __restrict__ H1P,
                                                 const short* __restrict__ WoutP,
                                                 const float* __restrict__ bout,
                                                 float* __restrict__ partials) {
  int bM = blockIdx.x, bN = blockIdx.y;
  int tid = threadIdx.x, w = tid >> 6, lane = tid & 63, q = lane >> 4, col = lane & 15;
  int wm = w >> 1, wn = w & 1;
  __shared__ __align__(16) short As[128 * 32];
  __shared__ __align__(16) short Bs[128 * 32];
  __shared__ float sred[128][2];
  f32x4 acc[4][4];
#pragma unroll
  for (int mi = 0; mi < 4; ++mi)
#pragma unroll
    for (int ni = 0; ni < 4; ++ni) acc[mi][ni] = (f32x4){0.f, 0.f, 0.f, 0.f};

  for (int ks = 0; ks < 17; ++ks) {
#pragma unroll
    for (int i = 0; i < 2; ++i) {
      int chunk = tid * 2 + i;               // 0..511
      int row = chunk >> 2, ch = chunk & 3;
      ((short8*)As)[chunk] = *(const short8*)(H1P  + (size_t)(bM * 128 + row) * KH + ks * 32 + ch * 8);
      ((short8*)Bs)[chunk] = *(const short8*)(WoutP + (size_t)(bN * 128 + row) * KH + ks * 32 + ch * 8);
    }
    __syncthreads();
    short8 af[4], bf[4];
#pragma unroll
    for (int mi = 0; mi < 4; ++mi) af[mi] = *(const short8*)(As + (wm * 64 + mi * 16 + col) * 32 + q * 8);
#pragma unroll
    for (int ni = 0; ni < 4; ++ni) bf[ni] = *(const short8*)(Bs + (wn * 64 + ni * 16 + col) * 32 + q * 8);
#pragma unroll
    for (int mi = 0; mi < 4; ++mi)
#pragma unroll
      for (int ni = 0; ni < 4; ++ni)
        acc[mi][ni] = __builtin_amdgcn_mfma_f32_16x16x32_bf16(af[mi], bf[ni], acc[mi][ni], 0, 0, 0);
    __syncthreads();
  }
  float bias[4];
#pragma unroll
  for (int ni = 0; ni < 4; ++ni) bias[ni] = bout[bN * 128 + wn * 64 + ni * 16 + col];
#pragma unroll
  for (int mi = 0; mi < 4; ++mi) {
#pragma unroll
    for (int r = 0; r < 4; ++r) {
      float s = 0.f;
#pragma unroll
      for (int ni = 0; ni < 4; ++ni) s += __expf(acc[mi][ni][r] + bias[ni]);
      s += __shfl_xor(s, 1, 64); s += __shfl_xor(s, 2, 64);
      s += __shfl_xor(s, 4, 64); s += __shfl_xor(s, 8, 64);
      if (col == 0) sred[wm * 64 + mi * 16 + q * 4 + r][wn] = s;
    }
  }
  __syncthreads();
  if (tid < 128)
    partials[(size_t)(bM * 128 + tid) * NBN + bN] = sred[tid][0] + sred[tid][1];
}

// ---------------- finish: lse + target logit + loss ----------------
__global__ void __launch_bounds__(256) k_finish(const float* __restrict__ partials,
                                                const short* __restrict__ H1P,
                                                const float* __restrict__ Wout,
                                                const float* __restrict__ bout,
                                                const int* __restrict__ y,
                                                float* __restrict__ out) {
  int tid = threadIdx.x, w = tid >> 6, lane = tid & 63;
  int row = blockIdx.x * 4 + w;           // 0..2047 (t*32+b)
  float s = 0.f;
  for (int j = lane; j < NBN; j += 64) s += partials[(size_t)row * NBN + j];
#pragma unroll
  for (int off = 32; off > 0; off >>= 1) s += __shfl_down(s, off, 64);
  int tok = y[row + 32];                  // y[(t+1)*32 + b]
  float d = 0.f;
  for (int k = lane; k < H; k += 64)
    d += bf2f(H1P[(size_t)row * KH + k]) * Wout[(size_t)tok * H + k];
#pragma unroll
  for (int off = 32; off > 0; off >>= 1) d += __shfl_down(d, off, 64);
  __shared__ float bsum[4];
  if (lane == 0) bsum[w] = __logf(s) - (d + bout[tok]);
  __syncthreads();
  if (tid == 0) atomicAdd(out, (bsum[0] + bsum[1] + bsum[2] + bsum[3]) * (1.f / 32.f));
}

// ---------------- host ----------------
extern "C" void kernel_launch(void* const* d_in, const int* in_sizes, int n_in,
                              void* d_out, int out_size, void* d_ws, size_t ws_size,
                              hipStream_t stream) {
  const int*   x      = (const int*)d_in[0];
  const int*   y      = (const int*)d_in[1];
  const float* encemb = (const float*)d_in[2];
  const float* decemb = (const float*)d_in[3];
  const float* eWih0  = (const float*)d_in[4];
  const float* eWhh0  = (const float*)d_in[5];
  const float* ebih0  = (const float*)d_in[6];
  const float* ebhh0  = (const float*)d_in[7];
  const float* eWih1  = (const float*)d_in[8];
  const float* eWhh1  = (const float*)d_in[9];
  const float* ebih1  = (const float*)d_in[10];
  const float* ebhh1  = (const float*)d_in[11];
  const float* dWih0  = (const float*)d_in[12];
  const float* dWhh0  = (const float*)d_in[13];
  const float* dbih0  = (const float*)d_in[14];
  const float* dbhh0  = (const float*)d_in[15];
  const float* dWih1  = (const float*)d_in[16];
  const float* dWhh1  = (const float*)d_in[17];
  const float* dbih1  = (const float*)d_in[18];
  const float* dbhh1  = (const float*)d_in[19];
  const float* Wout   = (const float*)d_in[20];
  const float* bout   = (const float*)d_in[21];
  float* out = (float*)d_out;

  char* wsb = (char*)d_ws;
  size_t off = 0;
  auto alloc = [&](size_t bytes) -> void* {
    void* p = wsb + off;
    off += (bytes + 255) & ~(size_t)255;
    return p;
  };
  short* WoutP = (short*)alloc((size_t)V * KH * 2);
  short* WAe   = (short*)alloc((size_t)NB * 17408 * 2);
  short* WBe   = (short*)alloc((size_t)NB * 34816 * 2);
  short* WAd   = (short*)alloc((size_t)NB * 17408 * 2);
  short* WBd   = (short*)alloc((size_t)NB * 34816 * 2);
  short* WihPe = (short*)alloc((size_t)GP * KE * 2);
  short* WihPd = (short*)alloc((size_t)GP * KE * 2);
  float* b0e   = (float*)alloc(GP * 4);
  float* b1e   = (float*)alloc(GP * 4);
  float* b0d   = (float*)alloc(GP * 4);
  float* b1d   = (float*)alloc(GP * 4);
  float* X0e   = (float*)alloc((size_t)SEQ * GP * SB * 4);
  float* X0d   = (float*)alloc((size_t)SEQ * GP * SB * 4);
  short* hst   = (short*)alloc((size_t)2 * 2 * 32 * KH * 2);  // [parity][layer][32][544]
  short* H1P   = (short*)alloc((size_t)MROW * KH * 2);
  float* parts = (float*)alloc((size_t)MROW * NBN * 4);
  unsigned* bar = (unsigned*)alloc(NB * 64);

  hipMemsetAsync(d_out, 0, sizeof(float), stream);
  hipMemsetAsync(hst, 0, (size_t)2 * 2 * 32 * KH * 2, stream);
  hipMemsetAsync(bar, 0, NB * 64, stream);

  k_pack_bias<<<(GP + 255) / 256, 256, 0, stream>>>(ebih0, ebhh0, ebih1, ebhh1,
                                                    dbih0, dbhh0, dbih1, dbhh1,
                                                    b0e, b1e, b0d, b1d);
  k_pack_wih<<<(GP * KE / 8 + 255) / 256, 256, 0, stream>>>(eWih0, WihPe);
  k_pack_wih<<<(GP * KE / 8 + 255) / 256, 256, 0, stream>>>(dWih0, WihPd);
  {
    int totA = NB * 2 * 17 * 64, totB = NB * 2 * 34 * 64;
    k_pack_gates<<<(totA + 255) / 256, 256, 0, stream>>>(eWhh0, eWhh0, WAe, 17);
    k_pack_gates<<<(totB + 255) / 256, 256, 0, stream>>>(eWih1, eWhh1, WBe, 34);
    k_pack_gates<<<(totA + 255) / 256, 256, 0, stream>>>(dWhh0, dWhh0, WAd, 17);
    k_pack_gates<<<(totB + 255) / 256, 256, 0, stream>>>(dWih1, dWhh1, WBd, 34);
  }
  k_pack_wout<<<(V * (KH / 8) + 255) / 256, 256, 0, stream>>>(Wout, WoutP);

  k_embproj<<<dim3(GP / 16, 32), 256, 0, stream>>>(WihPe, encemb, x, b0e, X0e);
  k_embproj<<<dim3(GP / 16, 32), 256, 0, stream>>>(WihPd, decemb, y, b0d, X0d);

  RecArgs ra{WAe, WBe, WAd, WBd, X0e, X0d, b1e, b1d, hst, H1P, bar};
  void* kargs[] = {&ra};
  hipLaunchCooperativeKernel((const void*)k_recur, dim3(NB), dim3(256), kargs, 0, stream);

  k_project<<<dim3(MROW / 128, NBN), 256, 0, stream>>>(H1P, WoutP, bout, parts);
  k_finish<<<MROW / 4, 256, 0, stream>>>(parts, H1P, Wout, bout, y, out);
}